// Round 2
// baseline (629.812 us; speedup 1.0000x reference)
//
#include <hip/hip_runtime.h>
#include <hip/hip_bf16.h>

// Bahdanau attention, restructured:
//   tanh_in[b,t,k] = e[b,t,:]@(U@Wa) + cvec[b,k]   (one 131072x512x512 bf16 GEMM)
//   cij[b,t] = sum_k tanh(tanh_in)*V[k]            (fused epilogue, no [B,T,H] tensor)
//   alphas = softmax(cij); out = sum_t alphas*e
// Shapes: B=32 T=4096 D=512 H=512.
//
// R2: GEMM tile 64(M) x 512(N-full) so e is fetched exactly once (FETCH 528->~290MB);
// B staged async via global_load_lds width=16 (m97 ladder); A staging shrunk to
// 4 float4/thread with XOR-swizzled LDS units (kills 8-way ds_write conflict).

#define BB 32
#define TT 4096
#define DD 512
#define HH 512
#define BK 64

typedef short s16x8 __attribute__((ext_vector_type(8)));
typedef float f32x4 __attribute__((ext_vector_type(4)));

union FU { float f; unsigned u; };

// truncate two f32 -> packed bf16 pair (lo=a, hi=b). Same error variance as RNE,
// zero net bias for sign-symmetric data.
static __device__ __forceinline__ unsigned pack_bf16_trunc(float a, float b) {
    FU ua, ub; ua.f = a; ub.f = b;
    return (ua.u >> 16) | (ub.u & 0xffff0000u);
}

static __device__ __forceinline__ unsigned short f2bf_rne(float x) {
    FU v; v.f = x;
    unsigned u = v.u;
    u = u + 0x7fffu + ((u >> 16) & 1u);
    return (unsigned short)(u >> 16);
}

static __device__ __forceinline__ float tanh_fast(float x) {
    float e = __expf(2.0f * x);
    return 1.0f - 2.0f * __builtin_amdgcn_rcpf(e + 1.0f);
}

// async global->LDS, 16B per lane. LDS dest = wave-uniform base + lane*16.
static __device__ __forceinline__ void gload_lds16(const void* g, void* l) {
    __builtin_amdgcn_global_load_lds(
        (const __attribute__((address_space(1))) unsigned int*)g,
        (__attribute__((address_space(3))) unsigned int*)l, 16, 0, 0);
}

// ---------------------------------------------------------------------------
// A1: g[b,h] = hidden[b,:]@W[:,h] + bias[h]
__global__ void k_dens1(const float* __restrict__ hs, const float* __restrict__ W,
                        const float* __restrict__ bias, float* __restrict__ g) {
    int bi = blockIdx.x;
    int dc = bi & 3, hb = (bi >> 2) & 1, b = bi >> 3;
    int h = hb * 256 + threadIdx.x;
    float s = (dc == 0) ? bias[h] : 0.0f;
    int d0 = dc * 128;
    #pragma unroll 4
    for (int d = 0; d < 128; ++d)
        s = fmaf(hs[b * DD + d0 + d], W[(size_t)(d0 + d) * HH + h], s);
    atomicAdd(&g[b * HH + h], s);
}

// A2: cvec[b,k] = g[b,:]@Wa[:,k] + ba[k]
__global__ void k_cvec(const float* __restrict__ g, const float* __restrict__ Wa,
                       const float* __restrict__ ba, float* __restrict__ cvec) {
    int bi = blockIdx.x;
    int hc = bi & 3, kb = (bi >> 2) & 1, b = bi >> 3;
    int k = kb * 256 + threadIdx.x;
    float s = (hc == 0) ? ba[k] : 0.0f;
    int h0 = hc * 128;
    #pragma unroll 4
    for (int h = 0; h < 128; ++h)
        s = fmaf(g[b * HH + h0 + h], Wa[(size_t)(h0 + h) * HH + k], s);
    atomicAdd(&cvec[b * HH + k], s);
}

// A3: UWaT[n][d] = bf16( sum_h U[d,h]*Wa[h,n] )  -- transposed for B-fragments
__global__ void k_uwa(const float* __restrict__ U, const float* __restrict__ Wa,
                      unsigned short* __restrict__ UWaT) {
    int d0 = blockIdx.x * 4;
    int tid = threadIdx.x;
    __shared__ float Us[4][DD];
    #pragma unroll
    for (int i = 0; i < 8; ++i) {
        int idx = i * 256 + tid;
        Us[idx >> 9][idx & 511] = U[(size_t)(d0 + (idx >> 9)) * HH + (idx & 511)];
    }
    __syncthreads();
    float acc[4][2] = {};
    #pragma unroll 4
    for (int h = 0; h < DD; ++h) {
        float w0 = Wa[(size_t)h * HH + tid];
        float w1 = Wa[(size_t)h * HH + 256 + tid];
        #pragma unroll
        for (int dd = 0; dd < 4; ++dd) {
            float u = Us[dd][h];
            acc[dd][0] = fmaf(u, w0, acc[dd][0]);
            acc[dd][1] = fmaf(u, w1, acc[dd][1]);
        }
    }
    #pragma unroll
    for (int dd = 0; dd < 4; ++dd) {
        UWaT[(size_t)tid * DD + d0 + dd] = f2bf_rne(acc[dd][0]);
        UWaT[(size_t)(tid + 256) * DD + d0 + dd] = f2bf_rne(acc[dd][1]);
    }
}

// ---------------------------------------------------------------------------
// B: GEMM tile 64(M) x 512(N full), BK=64. 4 waves, wave w -> cols [w*128,w*128+128).
// e rows fetched EXACTLY once. B (UWaT, bf16) staged async via global_load_lds.
// LDS 16B-unit layouts:  As unit = g*64 + (row^g)  (XOR swizzle, conflict-free)
//                        Bs unit = g*512 + col     (lane-contiguous for load_lds)
__global__ void __launch_bounds__(256, 2) k_gemm_tanh(
    const float* __restrict__ e, const unsigned short* __restrict__ Bt,
    const float* __restrict__ cvec, const float* __restrict__ V,
    float* __restrict__ cij) {
    int tid = threadIdx.x;
    int m0 = blockIdx.x * 64;          // 2048 blocks
    int lane = tid & 63, w = tid >> 6;
    int wn = w * 128;
    int lcol = lane & 15, q = lane >> 4;

    __shared__ __align__(16) unsigned short As[64 * BK];    // 8 KB
    __shared__ __align__(16) unsigned short Bs[512 * BK];   // 64 KB

    f32x4 acc[4][8] = {};

    const float* Abase = e + (size_t)m0 * DD;

    for (int k0 = 0; k0 < DD; k0 += BK) {
        // B: 8 g-units x 512 cols = 64 wave-instructions; wave w issues 16.
        #pragma unroll
        for (int u = 0; u < 16; ++u) {
            int p = w * 16 + u;
            int g = p >> 3, c0 = (p & 7) * 64;
            const unsigned short* gp = Bt + (size_t)(c0 + lane) * DD + k0 + g * 8;
            gload_lds16(gp, &Bs[(g * 512 + c0) * 8]);
        }
        // A: 64x64 fp32 -> bf16, 4 float4/thread, swizzled ds_write_b64.
        #pragma unroll
        for (int it = 0; it < 4; ++it) {
            int idx = it * 256 + tid;
            int row = idx >> 4, c4 = idx & 15;
            float4 v = *(const float4*)(Abase + (size_t)row * DD + k0 + c4 * 4);
            uint2 wv;
            wv.x = pack_bf16_trunc(v.x, v.y);
            wv.y = pack_bf16_trunc(v.z, v.w);
            int g = c4 >> 1, half = c4 & 1;
            *(uint2*)&As[(g * 64 + (row ^ g)) * 8 + half * 4] = wv;
        }
        __syncthreads();
        #pragma unroll
        for (int ks = 0; ks < BK; ks += 32) {
            int gk = ks >> 3;  // 0 or 4
            s16x8 af[4], bfr[8];
            #pragma unroll
            for (int i = 0; i < 4; ++i) {
                int row = i * 16 + lcol, g = gk + q;
                af[i] = *(const s16x8*)&As[(g * 64 + (row ^ g)) * 8];
            }
            #pragma unroll
            for (int j = 0; j < 8; ++j)
                bfr[j] = *(const s16x8*)&Bs[((gk + q) * 512 + wn + j * 16 + lcol) * 8];
            #pragma unroll
            for (int i = 0; i < 4; ++i)
                #pragma unroll
                for (int j = 0; j < 8; ++j)
                    acc[i][j] = __builtin_amdgcn_mfma_f32_16x16x32_bf16(
                        af[i], bfr[j], acc[i][j], 0, 0, 0);
        }
        __syncthreads();
    }

    // Epilogue: cij[row] += sum over this wave's 128 cols of tanh(acc+cvec)*V.
    // C/D layout: col = lane&15, row = (lane>>4)*4 + reg   [m89/m91 verified]
    int b = m0 >> 12;
    float cvv[8], Vv[8];
    #pragma unroll
    for (int j = 0; j < 8; ++j) {
        int h = wn + j * 16 + lcol;
        cvv[j] = cvec[b * HH + h];
        Vv[j] = V[h];
    }
    #pragma unroll
    for (int i = 0; i < 4; ++i) {
        #pragma unroll
        for (int r = 0; r < 4; ++r) {
            float s = 0.0f;
            #pragma unroll
            for (int j = 0; j < 8; ++j)
                s = fmaf(tanh_fast(acc[i][j][r] + cvv[j]), Vv[j], s);
            s += __shfl_xor(s, 1);
            s += __shfl_xor(s, 2);
            s += __shfl_xor(s, 4);
            s += __shfl_xor(s, 8);
            if (lcol == 0)
                atomicAdd(&cij[m0 + i * 16 + q * 4 + r], s);
        }
    }
}

// ---------------------------------------------------------------------------
// C1: softmax over T per batch.
__global__ void k_softmax(const float* __restrict__ cij, float* __restrict__ alphas) {
    int b = blockIdx.x, tid = threadIdx.x;
    const float* row = cij + (size_t)b * TT;
    __shared__ float red[4];
    float m = -1e30f;
    for (int t = tid; t < TT; t += 256) m = fmaxf(m, row[t]);
    #pragma unroll
    for (int o = 1; o < 64; o <<= 1) m = fmaxf(m, __shfl_xor(m, o));
    if ((tid & 63) == 0) red[tid >> 6] = m;
    __syncthreads();
    m = fmaxf(fmaxf(red[0], red[1]), fmaxf(red[2], red[3]));
    __syncthreads();
    float sum = 0.0f;
    for (int t = tid; t < TT; t += 256) sum += __expf(row[t] - m);
    #pragma unroll
    for (int o = 1; o < 64; o <<= 1) sum += __shfl_xor(sum, o);
    if ((tid & 63) == 0) red[tid >> 6] = sum;
    __syncthreads();
    float inv = 1.0f / (red[0] + red[1] + red[2] + red[3]);
    for (int t = tid; t < TT; t += 256)
        alphas[(size_t)b * TT + t] = __expf(row[t] - m) * inv;
}

// C2: out[b,d] = sum_t alphas[b,t]*e[b,t,d]. 268MB stream; 2048 blocks,
// 64 t-rows each, 2 independent row-streams per thread for ILP.
__global__ void k_wsum(const float* __restrict__ e, const float* __restrict__ alphas,
                       float* __restrict__ out) {
    int b = blockIdx.x >> 6;
    int t0 = (blockIdx.x & 63) * 64;
    int tid = threadIdx.x;
    int half = tid >> 7, f4 = tid & 127;
    const float* base = e + (size_t)b * TT * DD;
    const float* al = alphas + (size_t)b * TT;
    f32x4 a0 = {0, 0, 0, 0}, a1 = {0, 0, 0, 0};
    for (int it = 0; it < 16; ++it) {
        int t = t0 + it * 4 + half;
        float w0 = al[t], w1 = al[t + 2];
        f32x4 v0 = *(const f32x4*)(base + (size_t)t * DD + f4 * 4);
        f32x4 v1 = *(const f32x4*)(base + (size_t)(t + 2) * DD + f4 * 4);
        a0 += w0 * v0;
        a1 += w1 * v1;
    }
    a0 += a1;
    float* o = out + b * DD + f4 * 4;
    atomicAdd(o + 0, a0[0]);
    atomicAdd(o + 1, a0[1]);
    atomicAdd(o + 2, a0[2]);
    atomicAdd(o + 3, a0[3]);
}

// ---------------------------------------------------------------------------
extern "C" void kernel_launch(void* const* d_in, const int* in_sizes, int n_in,
                              void* d_out, int out_size, void* d_ws, size_t ws_size,
                              hipStream_t stream) {
    const float* hs   = (const float*)d_in[0];   // [32,512]
    const float* e    = (const float*)d_in[1];   // [32,4096,512]
    const float* W    = (const float*)d_in[2];   // [512,512]
    const float* U    = (const float*)d_in[3];   // [512,512]
    const float* V    = (const float*)d_in[4];   // [512]
    const float* bias = (const float*)d_in[5];   // [512]
    const float* Wa   = (const float*)d_in[6];   // [512,512]
    const float* ba   = (const float*)d_in[7];   // [512]

    float* out    = (float*)d_out;               // [32,512] then alphas [32,4096]
    float* alphas = out + BB * DD;

    float*          cij  = (float*)d_ws;                              // 512 KB
    float*          g    = (float*)((char*)d_ws + 524288);            // 64 KB
    float*          cvec = (float*)((char*)d_ws + 589824);            // 64 KB
    unsigned short* Bt   = (unsigned short*)((char*)d_ws + 655360);   // 512 KB bf16

    hipMemsetAsync(d_ws, 0, 655360, stream);              // cij + g + cvec
    hipMemsetAsync(d_out, 0, BB * DD * sizeof(float), stream);

    k_dens1<<<256, 256, 0, stream>>>(hs, W, bias, g);
    k_cvec<<<256, 256, 0, stream>>>(g, Wa, ba, cvec);
    k_uwa<<<128, 256, 0, stream>>>(U, Wa, Bt);
    k_gemm_tanh<<<2048, 256, 0, stream>>>(e, Bt, cvec, V, cij);
    k_softmax<<<BB, 256, 0, stream>>>(cij, alphas);
    k_wsum<<<BB * 64, 256, 0, stream>>>(e, alphas, out);
}

// Round 3
// 567.672 us; speedup vs baseline: 1.1095x; 1.1095x over previous
//
#include <hip/hip_runtime.h>
#include <hip/hip_bf16.h>

// Bahdanau attention, restructured:
//   tanh_in[b,t,k] = e[b,t,:]@(U@Wa) + cvec[b,k]   (one 131072x512x512 bf16 GEMM)
//   cij[b,t] = sum_k tanh(tanh_in)*V[k]            (fused epilogue, no [B,T,H] tensor)
//   alphas = softmax(cij); out = sum_t alphas*e
// Shapes: B=32 T=4096 D=512 H=512.
//
// R3: (a) B staging made COALESCED: each global_load_lds covers 8 B-rows x 8
// 16B-chunks (8 cachelines, = contiguous-1KB cost) with XOR chunk swizzle
// (g^row) so fragment ds_read_b128 lands <=2-way (free). R2's version touched
// 64 cachelines/instr (stride-1024 gather) -> VMEM-request-path bound at 12% MFMA.
// (b) k_wsum atomic storm (1M device atomics, 64-way/line cross-XCD) replaced by
// partial-sum stores + tiny reduce kernel.

#define BB 32
#define TT 4096
#define DD 512
#define HH 512
#define BK 64

typedef short s16x8 __attribute__((ext_vector_type(8)));
typedef float f32x4 __attribute__((ext_vector_type(4)));

union FU { float f; unsigned u; };

static __device__ __forceinline__ unsigned pack_bf16_trunc(float a, float b) {
    FU ua, ub; ua.f = a; ub.f = b;
    return (ua.u >> 16) | (ub.u & 0xffff0000u);
}

static __device__ __forceinline__ unsigned short f2bf_rne(float x) {
    FU v; v.f = x;
    unsigned u = v.u;
    u = u + 0x7fffu + ((u >> 16) & 1u);
    return (unsigned short)(u >> 16);
}

static __device__ __forceinline__ float tanh_fast(float x) {
    float e = __expf(2.0f * x);
    return 1.0f - 2.0f * __builtin_amdgcn_rcpf(e + 1.0f);
}

// async global->LDS, 16B/lane. LDS dest = wave-uniform base + lane*16.
static __device__ __forceinline__ void gload_lds16(const void* g, void* l) {
    __builtin_amdgcn_global_load_lds(
        (const __attribute__((address_space(1))) unsigned int*)g,
        (__attribute__((address_space(3))) unsigned int*)l, 16, 0, 0);
}

// ---------------------------------------------------------------------------
// A1: g[b,h] = hidden[b,:]@W[:,h] + bias[h]
__global__ void k_dens1(const float* __restrict__ hs, const float* __restrict__ W,
                        const float* __restrict__ bias, float* __restrict__ g) {
    int bi = blockIdx.x;
    int dc = bi & 3, hb = (bi >> 2) & 1, b = bi >> 3;
    int h = hb * 256 + threadIdx.x;
    float s = (dc == 0) ? bias[h] : 0.0f;
    int d0 = dc * 128;
    #pragma unroll 4
    for (int d = 0; d < 128; ++d)
        s = fmaf(hs[b * DD + d0 + d], W[(size_t)(d0 + d) * HH + h], s);
    atomicAdd(&g[b * HH + h], s);
}

// A2: cvec[b,k] = g[b,:]@Wa[:,k] + ba[k]
__global__ void k_cvec(const float* __restrict__ g, const float* __restrict__ Wa,
                       const float* __restrict__ ba, float* __restrict__ cvec) {
    int bi = blockIdx.x;
    int hc = bi & 3, kb = (bi >> 2) & 1, b = bi >> 3;
    int k = kb * 256 + threadIdx.x;
    float s = (hc == 0) ? ba[k] : 0.0f;
    int h0 = hc * 128;
    #pragma unroll 4
    for (int h = 0; h < 128; ++h)
        s = fmaf(g[b * HH + h0 + h], Wa[(size_t)(h0 + h) * HH + k], s);
    atomicAdd(&cvec[b * HH + k], s);
}

// A3: UWaT[n][d] = bf16( sum_h U[d,h]*Wa[h,n] ) -- transposed for B-fragments.
// 64 blocks x 8 d-rows (halves Wa re-reads vs 4-row version).
__global__ void k_uwa(const float* __restrict__ U, const float* __restrict__ Wa,
                      unsigned short* __restrict__ UWaT) {
    int d0 = blockIdx.x * 8;
    int tid = threadIdx.x;
    __shared__ float Us[8][DD];
    #pragma unroll
    for (int i = 0; i < 16; ++i) {
        int idx = i * 256 + tid;
        Us[idx >> 9][idx & 511] = U[(size_t)(d0 + (idx >> 9)) * HH + (idx & 511)];
    }
    __syncthreads();
    float acc[8][2] = {};
    #pragma unroll 2
    for (int h = 0; h < DD; ++h) {
        float w0 = Wa[(size_t)h * HH + tid];
        float w1 = Wa[(size_t)h * HH + 256 + tid];
        #pragma unroll
        for (int dd = 0; dd < 8; ++dd) {
            float u = Us[dd][h];
            acc[dd][0] = fmaf(u, w0, acc[dd][0]);
            acc[dd][1] = fmaf(u, w1, acc[dd][1]);
        }
    }
    #pragma unroll
    for (int dd = 0; dd < 8; ++dd) {
        UWaT[(size_t)tid * DD + d0 + dd] = f2bf_rne(acc[dd][0]);
        UWaT[(size_t)(tid + 256) * DD + d0 + dd] = f2bf_rne(acc[dd][1]);
    }
}

// ---------------------------------------------------------------------------
// B: GEMM tile 64(M) x 512(N full), BK=64. 4 waves, wave w -> cols [w*128, +128).
// e rows fetched EXACTLY once (43us HBM floor). B (UWaT bf16) staged per k0 via
// coalesced global_load_lds: one instr = 8 rows x 8 chunks of 16B (8 cachelines),
// lane l = (row_local = l>>3, gg = l&7) reads chunk g_src = gg ^ row_local.
// LDS 16B-unit layouts:
//   Bs unit = col*8 + (g ^ (col&7))   (XOR swizzle -> frag reads <=2-way, free)
//   As unit = g*64 + (row ^ g)        (conflict-free, measured 0 in R2)
__global__ void __launch_bounds__(256, 2) k_gemm_tanh(
    const float* __restrict__ e, const unsigned short* __restrict__ Bt,
    const float* __restrict__ cvec, const float* __restrict__ V,
    float* __restrict__ cij) {
    int tid = threadIdx.x;
    int m0 = blockIdx.x * 64;          // 2048 blocks
    int lane = tid & 63, w = tid >> 6;
    int wn = w * 128;
    int lcol = lane & 15, q = lane >> 4;
    int rl = lane >> 3, gg = lane & 7;           // B-staging lane decomposition

    __shared__ __align__(16) unsigned short As[64 * BK];    // 8 KB
    __shared__ __align__(16) unsigned short Bs[512 * BK];   // 64 KB

    f32x4 acc[4][8] = {};

    const float* Abase = e + (size_t)m0 * DD;

    for (int k0 = 0; k0 < DD; k0 += BK) {
        // A: issue the 4 HBM float4 loads first (longest latency).
        float4 av[4];
        #pragma unroll
        for (int it = 0; it < 4; ++it) {
            int idx = it * 256 + tid;
            int row = idx >> 4, c4 = idx & 15;
            av[it] = *(const float4*)(Abase + (size_t)row * DD + k0 + c4 * 4);
        }
        // B: 16 coalesced global_load_lds per wave; wave w stages rows [w*128,+128).
        #pragma unroll
        for (int u = 0; u < 16; ++u) {
            int n0 = w * 128 + u * 8;
            const unsigned short* gp =
                Bt + (size_t)(n0 + rl) * DD + k0 + ((gg ^ rl) << 3);
            gload_lds16(gp, &Bs[n0 * 64]);
        }
        // A: convert + swizzled ds_write.
        #pragma unroll
        for (int it = 0; it < 4; ++it) {
            int idx = it * 256 + tid;
            int row = idx >> 4, c4 = idx & 15;
            uint2 wv;
            wv.x = pack_bf16_trunc(av[it].x, av[it].y);
            wv.y = pack_bf16_trunc(av[it].z, av[it].w);
            int g = c4 >> 1, half = c4 & 1;
            *(uint2*)&As[(g * 64 + (row ^ g)) * 8 + half * 4] = wv;
        }
        __syncthreads();
        #pragma unroll
        for (int ks = 0; ks < BK; ks += 32) {
            int gk = ks >> 3;  // 0 or 4
            s16x8 af[4], bfr[8];
            #pragma unroll
            for (int i = 0; i < 4; ++i) {
                int row = i * 16 + lcol, g = gk + q;
                af[i] = *(const s16x8*)&As[(g * 64 + (row ^ g)) * 8];
            }
            #pragma unroll
            for (int j = 0; j < 8; ++j) {
                int col = wn + j * 16 + lcol, g = gk + q;
                bfr[j] = *(const s16x8*)&Bs[col * 64 + ((g ^ (col & 7)) << 3)];
            }
            #pragma unroll
            for (int i = 0; i < 4; ++i)
                #pragma unroll
                for (int j = 0; j < 8; ++j)
                    acc[i][j] = __builtin_amdgcn_mfma_f32_16x16x32_bf16(
                        af[i], bfr[j], acc[i][j], 0, 0, 0);
        }
        __syncthreads();
    }

    // Epilogue: cij[row] += sum over this wave's 128 cols of tanh(acc+cvec)*V.
    // C/D layout: col = lane&15, row = (lane>>4)*4 + reg
    int b = m0 >> 12;
    float cvv[8], Vv[8];
    #pragma unroll
    for (int j = 0; j < 8; ++j) {
        int h = wn + j * 16 + lcol;
        cvv[j] = cvec[b * HH + h];
        Vv[j] = V[h];
    }
    #pragma unroll
    for (int i = 0; i < 4; ++i) {
        #pragma unroll
        for (int r = 0; r < 4; ++r) {
            float s = 0.0f;
            #pragma unroll
            for (int j = 0; j < 8; ++j)
                s = fmaf(tanh_fast(acc[i][j][r] + cvv[j]), Vv[j], s);
            s += __shfl_xor(s, 1);
            s += __shfl_xor(s, 2);
            s += __shfl_xor(s, 4);
            s += __shfl_xor(s, 8);
            if (lcol == 0)
                atomicAdd(&cij[m0 + i * 16 + q * 4 + r], s);
        }
    }
}

// ---------------------------------------------------------------------------
// C1: softmax over T per batch.
__global__ void k_softmax(const float* __restrict__ cij, float* __restrict__ alphas) {
    int b = blockIdx.x, tid = threadIdx.x;
    const float* row = cij + (size_t)b * TT;
    __shared__ float red[4];
    float m = -1e30f;
    for (int t = tid; t < TT; t += 256) m = fmaxf(m, row[t]);
    #pragma unroll
    for (int o = 1; o < 64; o <<= 1) m = fmaxf(m, __shfl_xor(m, o));
    if ((tid & 63) == 0) red[tid >> 6] = m;
    __syncthreads();
    m = fmaxf(fmaxf(red[0], red[1]), fmaxf(red[2], red[3]));
    __syncthreads();
    float sum = 0.0f;
    for (int t = tid; t < TT; t += 256) sum += __expf(row[t] - m);
    #pragma unroll
    for (int o = 1; o < 64; o <<= 1) sum += __shfl_xor(sum, o);
    if ((tid & 63) == 0) red[tid >> 6] = sum;
    __syncthreads();
    float inv = 1.0f / (red[0] + red[1] + red[2] + red[3]);
    for (int t = tid; t < TT; t += 256)
        alphas[(size_t)b * TT + t] = __expf(row[t] - m) * inv;
}

// C2a: partial weighted sums, NO atomics. block = (b, chunk of 64 t's);
// writes pw[b][chunk][d] (4 MB). 2048 blocks, 268MB HBM stream.
__global__ void k_wsum(const float* __restrict__ e, const float* __restrict__ alphas,
                       float* __restrict__ pw) {
    int b = blockIdx.x >> 6;
    int chunk = blockIdx.x & 63;
    int t0 = chunk * 64;
    int tid = threadIdx.x;
    int half = tid >> 7, f4 = tid & 127;
    const float* base = e + (size_t)b * TT * DD;
    const float* al = alphas + (size_t)b * TT;
    f32x4 a0 = {0, 0, 0, 0}, a1 = {0, 0, 0, 0};
    for (int it = 0; it < 16; ++it) {
        int t = t0 + it * 4 + half;
        float w0 = al[t], w1 = al[t + 2];
        f32x4 v0 = *(const f32x4*)(base + (size_t)t * DD + f4 * 4);
        f32x4 v1 = *(const f32x4*)(base + (size_t)(t + 2) * DD + f4 * 4);
        a0 += w0 * v0;
        a1 += w1 * v1;
    }
    a0 += a1;
    __shared__ f32x4 red[128];
    if (half == 1) red[f4] = a0;
    __syncthreads();
    if (half == 0) {
        a0 += red[f4];
        *(f32x4*)&pw[((size_t)(b * 64 + chunk)) * DD + f4 * 4] = a0;
    }
}

// C2b: out[b,d] = sum_chunk pw[b][chunk][d]. 4MB read, trivial.
__global__ void k_wred(const float* __restrict__ pw, float* __restrict__ out) {
    int b = blockIdx.x, tid = threadIdx.x;
    float2 acc = {0.0f, 0.0f};
    const float* base = pw + (size_t)b * 64 * DD;
    #pragma unroll 4
    for (int c = 0; c < 64; ++c) {
        float2 v = *(const float2*)(base + (size_t)c * DD + tid * 2);
        acc.x += v.x;
        acc.y += v.y;
    }
    *(float2*)&out[b * DD + tid * 2] = acc;
}

// ---------------------------------------------------------------------------
extern "C" void kernel_launch(void* const* d_in, const int* in_sizes, int n_in,
                              void* d_out, int out_size, void* d_ws, size_t ws_size,
                              hipStream_t stream) {
    const float* hs   = (const float*)d_in[0];   // [32,512]
    const float* e    = (const float*)d_in[1];   // [32,4096,512]
    const float* W    = (const float*)d_in[2];   // [512,512]
    const float* U    = (const float*)d_in[3];   // [512,512]
    const float* V    = (const float*)d_in[4];   // [512]
    const float* bias = (const float*)d_in[5];   // [512]
    const float* Wa   = (const float*)d_in[6];   // [512,512]
    const float* ba   = (const float*)d_in[7];   // [512]

    float* out    = (float*)d_out;               // [32,512] then alphas [32,4096]
    float* alphas = out + BB * DD;

    float*          cij  = (float*)d_ws;                              // 512 KB
    float*          g    = (float*)((char*)d_ws + 524288);            // 64 KB
    float*          cvec = (float*)((char*)d_ws + 589824);            // 64 KB
    unsigned short* Bt   = (unsigned short*)((char*)d_ws + 655360);   // 512 KB bf16
    float*          pw   = (float*)((char*)d_ws + 1179648);           // 4 MB

    hipMemsetAsync(d_ws, 0, 655360, stream);     // cij + g + cvec (atomic accums)

    k_dens1<<<256, 256, 0, stream>>>(hs, W, bias, g);
    k_cvec<<<256, 256, 0, stream>>>(g, Wa, ba, cvec);
    k_uwa<<<64, 256, 0, stream>>>(U, Wa, Bt);
    k_gemm_tanh<<<2048, 256, 0, stream>>>(e, Bt, cvec, V, cij);
    k_softmax<<<BB, 256, 0, stream>>>(cij, alphas);
    k_wsum<<<BB * 64, 256, 0, stream>>>(e, alphas, pw);
    k_wred<<<BB, 256, 0, stream>>>(pw, out);
}